// Round 5
// baseline (185.241 us; speedup 1.0000x reference)
//
#include <hip/hip_runtime.h>
#include <hip/hip_cooperative_groups.h>

namespace cg = cooperative_groups;

#define ALPHA 0.2f
#define NEG_INF -9.0e15f

constexpr int N = 1024;
constexpr int F = 64;
constexpr int TI = 4;          // rows per block
constexpr int NB = N / TI;     // 256 blocks (1 per CU)
constexpr int NT = 1024;       // threads per block
constexpr int NW = NT / 64;    // 16 waves

// Fused GAT layer: phase 1 computes Wh (this block's TI rows) + e1 (local) +
// e2 (global); grid-wide sync; phase 2 does masked-softmax attention + att@Wh + ELU.
__global__ __launch_bounds__(NT) void gat_fused(const float* __restrict__ h,
                                                const int* __restrict__ adj,
                                                const float* __restrict__ W,
                                                const float* __restrict__ a,
                                                float* __restrict__ Wh,
                                                float* __restrict__ e2g,
                                                float* __restrict__ out) {
    const int i0 = blockIdx.x * TI;
    const int t = threadIdx.x;       // 0..1023
    const int wave = t >> 6;         // 0..15
    const int lane = t & 63;

    __shared__ float hs[TI][F];           // 1 KB
    __shared__ float e1s[TI];
    __shared__ float e2s[N];              // 4 KB
    __shared__ float p[TI][N];            // 16 KB
    __shared__ float redmax[NW][TI];      // 256 B
    __shared__ float redsum[NW][TI];      // 256 B
    __shared__ float accs[NW][TI][F];     // 16 KB

    // ---- phase 1: Wh rows i0..i0+TI-1, e1 -> LDS, e2 -> global ----
    if (t < TI * F) hs[t >> 6][t & 63] = h[i0 * F + t];
    __syncthreads();
    if (t < TI * F) {
        const int r = t >> 6;
        const int f = t & 63;
        float acc = 0.f;
        #pragma unroll
        for (int k = 0; k < F; ++k) {
            // hs[r][k]: LDS broadcast within wave; W row: coalesced, L2-hot
            acc += hs[r][k] * W[k * F + f];
        }
        Wh[(size_t)(i0 + r) * F + f] = acc;

        float v1 = acc * a[f];
        float v2 = acc * a[F + f];
        #pragma unroll
        for (int off = 32; off > 0; off >>= 1) {
            v1 += __shfl_down(v1, off);
            v2 += __shfl_down(v2, off);
        }
        if (f == 0) {
            e1s[r] = v1;          // consumed only by this block
            e2g[i0 + r] = v2;     // consumed by every block
        }
    }
    __threadfence();
    cg::this_grid().sync();           // Wh + e2 now globally visible

    // ---- phase 2 ----
    e2s[t] = e2g[t];                  // NT == N: one element per thread
    __syncthreads();

    // pass 1: masked leaky-relu scores + per-row max (j == t exactly)
    float lmax[TI];
    #pragma unroll
    for (int r = 0; r < TI; ++r) {
        float e = e1s[r] + e2s[t];
        e = (e > 0.f) ? e : ALPHA * e;
        float s = (adj[(size_t)(i0 + r) * N + t] > 0) ? e : NEG_INF;
        p[r][t] = s;
        lmax[r] = s;
    }
    #pragma unroll
    for (int off = 32; off > 0; off >>= 1) {
        #pragma unroll
        for (int r = 0; r < TI; ++r)
            lmax[r] = fmaxf(lmax[r], __shfl_down(lmax[r], off));
    }
    if (lane == 0) {
        #pragma unroll
        for (int r = 0; r < TI; ++r) redmax[wave][r] = lmax[r];
    }
    __syncthreads();

    // pass 2: exp + per-row sum
    float m[TI], lsum[TI];
    #pragma unroll
    for (int r = 0; r < TI; ++r) {
        float mm = redmax[0][r];
        #pragma unroll
        for (int w = 1; w < NW; ++w) mm = fmaxf(mm, redmax[w][r]);
        m[r] = mm;
    }
    #pragma unroll
    for (int r = 0; r < TI; ++r) {
        float pe = __expf(p[r][t] - m[r]);
        p[r][t] = pe;
        lsum[r] = pe;
    }
    #pragma unroll
    for (int off = 32; off > 0; off >>= 1) {
        #pragma unroll
        for (int r = 0; r < TI; ++r)
            lsum[r] += __shfl_down(lsum[r], off);
    }
    if (lane == 0) {
        #pragma unroll
        for (int r = 0; r < TI; ++r) redsum[wave][r] = lsum[r];
    }
    __syncthreads();

    // pass 3: wave w covers j in [w*64, w*64+64); lane = feature f.
    // TI rows share each coalesced Wh load (p[r][j] is a free LDS broadcast).
    float a0 = 0.f, a1 = 0.f, a2 = 0.f, a3 = 0.f;
    const int j0 = wave * 64;
    for (int j = j0; j < j0 + 64; j += 4) {
        const float4 p0 = *(const float4*)&p[0][j];
        const float4 p1 = *(const float4*)&p[1][j];
        const float4 p2 = *(const float4*)&p[2][j];
        const float4 p3 = *(const float4*)&p[3][j];
        #pragma unroll
        for (int u = 0; u < 4; ++u) {
            const float whv = Wh[(size_t)(j + u) * F + lane];
            a0 += (&p0.x)[u] * whv;
            a1 += (&p1.x)[u] * whv;
            a2 += (&p2.x)[u] * whv;
            a3 += (&p3.x)[u] * whv;
        }
    }
    accs[wave][0][lane] = a0;
    accs[wave][1][lane] = a1;
    accs[wave][2][lane] = a2;
    accs[wave][3][lane] = a3;
    __syncthreads();

    // epilogue: reduce 16 waves, divide, ELU, store
    if (t < TI * F) {
        const int r = t >> 6;
        const int f = t & 63;
        float s = 0.f, dn = 0.f;
        #pragma unroll
        for (int w = 0; w < NW; ++w) {
            s += accs[w][r][f];
            dn += redsum[w][r];
        }
        const float hp = s / dn;
        out[(size_t)(i0 + r) * F + f] = (hp > 0.f) ? hp : expm1f(hp);
    }
}

extern "C" void kernel_launch(void* const* d_in, const int* in_sizes, int n_in,
                              void* d_out, int out_size, void* d_ws, size_t ws_size,
                              hipStream_t stream) {
    const float* h   = (const float*)d_in[0];
    const int*   adj = (const int*)d_in[1];
    const float* W   = (const float*)d_in[2];
    const float* a   = (const float*)d_in[3];
    float* out       = (float*)d_out;

    float* ws = (float*)d_ws;
    float* Wh = ws;            // N*F floats
    float* e2 = ws + N * F;    // N floats

    void* args[] = {(void*)&h, (void*)&adj, (void*)&W, (void*)&a,
                    (void*)&Wh, (void*)&e2, (void*)&out};
    hipLaunchCooperativeKernel((void*)gat_fused, dim3(NB), dim3(NT), args, 0, stream);
}

// Round 6
// 69.779 us; speedup vs baseline: 2.6547x; 2.6547x over previous
//
#include <hip/hip_runtime.h>

#define ALPHA 0.2f

constexpr int N = 1024;
constexpr int F = 64;
constexpr int TI = 4;          // rows per block in k2
constexpr int NT = 1024;       // k2 threads (== N: one j per thread in exp sweep)
constexpr int NW = NT / 64;    // 16 waves

// K1: Wh = h @ W (row per wave), e1 = Wh@a1, e2 = Wh@a2
// grid: 256 blocks, 256 threads (wave w -> row blockIdx*4+w)
__global__ __launch_bounds__(256) void k1_wh(const float* __restrict__ h,
                                             const float* __restrict__ W,
                                             const float* __restrict__ a,
                                             float* __restrict__ Wh,
                                             float* __restrict__ e1,
                                             float* __restrict__ e2) {
    const int wave = threadIdx.x >> 6;
    const int lane = threadIdx.x & 63;
    const int i = blockIdx.x * 4 + wave;

    const float hv = h[i * F + lane];   // lane holds h[i][lane]
    float acc = 0.f;
    #pragma unroll
    for (int k = 0; k < F; ++k) {
        // broadcast h[i][k] from lane k; W row read coalesced across lanes
        acc += __shfl(hv, k) * W[k * F + lane];
    }
    Wh[i * F + lane] = acc;

    float v1 = acc * a[lane];
    float v2 = acc * a[F + lane];
    #pragma unroll
    for (int off = 32; off > 0; off >>= 1) {
        v1 += __shfl_down(v1, off);
        v2 += __shfl_down(v2, off);
    }
    if (lane == 0) {
        e1[i] = v1;
        e2[i] = v2;
    }
}

// K2: TI rows/block, no-max softmax (exact up to fp rounding for |score| <~ 80).
// sweep A: w[i][j] = adj ? exp(leaky(e1+e2)) : 0  (one j per thread) + row sums
// sweep B: h_prime = w @ Wh, divide by sum, ELU.
__global__ __launch_bounds__(NT) void k2_attn(const int* __restrict__ adj,
                                              const float* __restrict__ Wh,
                                              const float* __restrict__ e1,
                                              const float* __restrict__ e2,
                                              float* __restrict__ out) {
    const int i0 = blockIdx.x * TI;
    const int t = threadIdx.x;       // 0..1023 == j in sweep A
    const int wave = t >> 6;         // 0..15
    const int lane = t & 63;

    __shared__ float e2s[N];              // 4 KB
    __shared__ float e1s[TI];
    __shared__ float p[TI][N];            // 16 KB: exp-weights
    __shared__ float redsum[NW][TI];      // 256 B
    __shared__ float accs[NW][TI][F];     // 16 KB

    e2s[t] = e2[t];
    if (t < TI) e1s[t] = e1[i0 + t];
    __syncthreads();

    // ---- sweep A ----
    const float ev = e2s[t];
    float lsum[TI];
    #pragma unroll
    for (int r = 0; r < TI; ++r) {
        float s = e1s[r] + ev;
        s = (s > 0.f) ? s : ALPHA * s;
        const float pe = (adj[(size_t)(i0 + r) * N + t] > 0) ? __expf(s) : 0.f;
        p[r][t] = pe;
        lsum[r] = pe;
    }
    #pragma unroll
    for (int off = 32; off > 0; off >>= 1) {
        #pragma unroll
        for (int r = 0; r < TI; ++r)
            lsum[r] += __shfl_down(lsum[r], off);
    }
    if (lane == 0) {
        #pragma unroll
        for (int r = 0; r < TI; ++r) redsum[wave][r] = lsum[r];
    }
    __syncthreads();

    // ---- sweep B: wave w covers j in [w*64, w*64+64); lane = feature f ----
    // TI rows share each coalesced Wh load; p[r][j] is a free LDS broadcast.
    float a0 = 0.f, a1 = 0.f, a2 = 0.f, a3 = 0.f;
    const int j0 = wave * 64;
    #pragma unroll 4
    for (int j = j0; j < j0 + 64; j += 4) {
        const float4 p0 = *(const float4*)&p[0][j];
        const float4 p1 = *(const float4*)&p[1][j];
        const float4 p2 = *(const float4*)&p[2][j];
        const float4 p3 = *(const float4*)&p[3][j];
        #pragma unroll
        for (int u = 0; u < 4; ++u) {
            const float whv = Wh[(size_t)(j + u) * F + lane];
            a0 += (&p0.x)[u] * whv;
            a1 += (&p1.x)[u] * whv;
            a2 += (&p2.x)[u] * whv;
            a3 += (&p3.x)[u] * whv;
        }
    }
    accs[wave][0][lane] = a0;
    accs[wave][1][lane] = a1;
    accs[wave][2][lane] = a2;
    accs[wave][3][lane] = a3;
    __syncthreads();

    // ---- epilogue: reduce 16 waves, divide, ELU, store ----
    if (t < TI * F) {
        const int r = t >> 6;
        const int f = t & 63;
        float s = 0.f, dn = 0.f;
        #pragma unroll
        for (int w = 0; w < NW; ++w) {
            s += accs[w][r][f];
            dn += redsum[w][r];
        }
        const float hp = s / dn;
        out[(size_t)(i0 + r) * F + f] = (hp > 0.f) ? hp : expm1f(hp);
    }
}

extern "C" void kernel_launch(void* const* d_in, const int* in_sizes, int n_in,
                              void* d_out, int out_size, void* d_ws, size_t ws_size,
                              hipStream_t stream) {
    const float* h   = (const float*)d_in[0];
    const int*   adj = (const int*)d_in[1];
    const float* W   = (const float*)d_in[2];
    const float* a   = (const float*)d_in[3];
    float* out       = (float*)d_out;

    float* ws = (float*)d_ws;
    float* Wh = ws;                  // N*F floats
    float* e1 = ws + N * F;          // N floats
    float* e2 = ws + N * F + N;      // N floats

    k1_wh<<<256, 256, 0, stream>>>(h, W, a, Wh, e1, e2);
    k2_attn<<<N / TI, NT, 0, stream>>>(adj, Wh, e1, e2, out);
}